// Round 1
// baseline (530.332 us; speedup 1.0000x reference)
//
#include <hip/hip_runtime.h>

#define N_NODES 100000
#define N_EDGES 3200000
#define BATCH   16
#define HIDDEN  64

// ---------------------------------------------------------------------------
// Phase 1: scatter. One thread per (edge, batch): tid = e*16 + b.
// Lanes 0..15 of a 16-thread group share an edge -> agg[r*16 + 0..15] is one
// contiguous 64B segment, so the 16 atomics from a group hit a single L2 line.
// deg is bumped once per edge (b==0 lane).
// ---------------------------------------------------------------------------
__global__ __launch_bounds__(256) void scatter_kernel(
    const int* __restrict__ ei,   // [2, E] row-major: ei[0..E-1]=row, ei[E..2E-1]=col
    const float* __restrict__ mu, // [B, N]
    float* __restrict__ agg,      // [N, B]
    float* __restrict__ deg) {    // [N]
  int tid = blockIdx.x * blockDim.x + threadIdx.x;
  if (tid >= N_EDGES * BATCH) return;
  int e = tid >> 4;
  int b = tid & 15;
  int r = ei[e];
  int c = ei[N_EDGES + e];
  float v = mu[b * N_NODES + c];
  atomicAdd(&agg[r * BATCH + b], v);
  if (b == 0) atomicAdd(&deg[r], 1.0f);
}

// ---------------------------------------------------------------------------
// Phase 2: normalize + per-scalar MLP (1 -> 64 -> 1, exact erf GELU).
// One thread per node, all 16 batches in registers.
//   reads  agg[n*16 .. n*16+15] : float4 x4, fully coalesced across the wave
//   writes out[b*N + n]         : coalesced across the wave per b
// ---------------------------------------------------------------------------
__global__ __launch_bounds__(256) void mlp_kernel(
    const float* __restrict__ agg, const float* __restrict__ deg,
    const float* __restrict__ W1, const float* __restrict__ b1,
    const float* __restrict__ W2, const float* __restrict__ b2,
    float* __restrict__ out) {
  __shared__ float sW1[HIDDEN], sB1[HIDDEN], sW2[HIDDEN];
  int t = threadIdx.x;
  if (t < HIDDEN) {
    sW1[t] = W1[t];
    sB1[t] = b1[t];
    sW2[t] = W2[t];
  }
  __syncthreads();

  int n = blockIdx.x * blockDim.x + t;
  if (n >= N_NODES) return;

  float d = fmaxf(deg[n], 1.0f);
  float dinv = 1.0f / d;

  float xd[BATCH];
  const float4* av = (const float4*)(agg + (size_t)n * BATCH);
#pragma unroll
  for (int i = 0; i < 4; ++i) {
    float4 v = av[i];
    xd[4 * i + 0] = v.x * dinv;
    xd[4 * i + 1] = v.y * dinv;
    xd[4 * i + 2] = v.z * dinv;
    xd[4 * i + 3] = v.w * dinv;
  }

  float acc[BATCH];
  float bias2 = b2[0];
#pragma unroll
  for (int b = 0; b < BATCH; ++b) acc[b] = bias2;

  for (int h = 0; h < HIDDEN; ++h) {
    float w1 = sW1[h], bb = sB1[h], w2 = sW2[h];
#pragma unroll
    for (int b = 0; b < BATCH; ++b) {
      float z = fmaf(xd[b], w1, bb);
      // exact GELU: 0.5*z*(1+erf(z/sqrt(2)))
      float g = 0.5f * z * (1.0f + erff(z * 0.70710678118654752f));
      acc[b] = fmaf(g, w2, acc[b]);
    }
  }

#pragma unroll
  for (int b = 0; b < BATCH; ++b) out[b * N_NODES + n] = acc[b];
}

extern "C" void kernel_launch(void* const* d_in, const int* in_sizes, int n_in,
                              void* d_out, int out_size, void* d_ws, size_t ws_size,
                              hipStream_t stream) {
  const float* mu = (const float*)d_in[0];
  const int*   ei = (const int*)d_in[1];
  const float* W1 = (const float*)d_in[2];
  const float* b1 = (const float*)d_in[3];
  const float* W2 = (const float*)d_in[4];
  const float* b2 = (const float*)d_in[5];
  float* out = (float*)d_out;

  float* agg = (float*)d_ws;                       // [N_NODES * BATCH]
  float* deg = agg + (size_t)N_NODES * BATCH;      // [N_NODES]

  size_t zero_bytes = ((size_t)N_NODES * BATCH + N_NODES) * sizeof(float);
  hipMemsetAsync(d_ws, 0, zero_bytes, stream);

  int total = N_EDGES * BATCH;
  scatter_kernel<<<(total + 255) / 256, 256, 0, stream>>>(ei, mu, agg, deg);
  mlp_kernel<<<(N_NODES + 255) / 256, 256, 0, stream>>>(agg, deg, W1, b1, W2, b2, out);
}

// Round 2
// 419.146 us; speedup vs baseline: 1.2653x; 1.2653x over previous
//
#include <hip/hip_runtime.h>

#define N_NODES 100000
#define N_EDGES 3200000
#define BATCH   16
#define HIDDEN  64

#define LUT_SIZE  8192
#define LUT_LO    (-16.0f)
#define LUT_SCALE (LUT_SIZE / 32.0f)   /* 256 entries per unit x */

// ---------------------------------------------------------------------------
// mu [B, N] -> mu_t [N, B]. One thread per node: 16 coalesced reads (per b),
// 4 coalesced float4 writes.
// ---------------------------------------------------------------------------
__global__ __launch_bounds__(256) void transpose_kernel(
    const float* __restrict__ mu, float* __restrict__ mu_t) {
  int n = blockIdx.x * blockDim.x + threadIdx.x;
  if (n >= N_NODES) return;
  float4 o[4];
#pragma unroll
  for (int q = 0; q < 4; ++q) {
    o[q].x = mu[(q * 4 + 0) * N_NODES + n];
    o[q].y = mu[(q * 4 + 1) * N_NODES + n];
    o[q].z = mu[(q * 4 + 2) * N_NODES + n];
    o[q].w = mu[(q * 4 + 3) * N_NODES + n];
  }
  float4* dst = (float4*)(mu_t + (size_t)n * BATCH);
#pragma unroll
  for (int q = 0; q < 4; ++q) dst[q] = o[q];
}

// ---------------------------------------------------------------------------
// Build LUT of the scalar MLP f(x) = W2^T gelu(x*W1 + b1) + b2 (exact erf),
// LUT_SIZE+1 knots over [LUT_LO, LUT_LO + 32].
// ---------------------------------------------------------------------------
__global__ __launch_bounds__(256) void build_lut_kernel(
    const float* __restrict__ W1, const float* __restrict__ b1,
    const float* __restrict__ W2, const float* __restrict__ b2,
    float* __restrict__ lut) {
  int i = blockIdx.x * blockDim.x + threadIdx.x;
  if (i > LUT_SIZE) return;
  float x = LUT_LO + (float)i / LUT_SCALE;
  float acc = b2[0];
  for (int h = 0; h < HIDDEN; ++h) {
    float z = fmaf(x, W1[h], b1[h]);
    float g = 0.5f * z * (1.0f + erff(z * 0.70710678118654752f));
    acc = fmaf(g, W2[h], acc);
  }
  lut[i] = acc;
}

// ---------------------------------------------------------------------------
// Scatter: tid = e*16 + b. The 16 lanes of an edge read ONE 64B line of
// mu_t[c*16 + 0..15] and atomicAdd ONE 64B line of agg[r*16 + 0..15].
// ---------------------------------------------------------------------------
__global__ __launch_bounds__(256) void scatter_kernel(
    const int* __restrict__ ei, const float* __restrict__ mu_t,
    float* __restrict__ agg, float* __restrict__ deg) {
  long long tid = (long long)blockIdx.x * blockDim.x + threadIdx.x;
  if (tid >= (long long)N_EDGES * BATCH) return;
  int e = (int)(tid >> 4);
  int b = (int)(tid & 15);
  int r = ei[e];
  int c = ei[N_EDGES + e];
  float v = mu_t[(size_t)c * BATCH + b];
  atomicAdd(&agg[(size_t)r * BATCH + b], v);
  if (b == 0) atomicAdd(&deg[r], 1.0f);
}

// ---------------------------------------------------------------------------
// Normalize + LUT-interp MLP. One thread per node, LUT staged in LDS (32.8KB
// -> still 4 blocks/CU with 160KB LDS).
// ---------------------------------------------------------------------------
__global__ __launch_bounds__(256) void apply_kernel(
    const float* __restrict__ agg, const float* __restrict__ deg,
    const float* __restrict__ lut, float* __restrict__ out) {
  __shared__ float slut[LUT_SIZE + 1];
  int t = threadIdx.x;
  for (int i = t; i <= LUT_SIZE; i += 256) slut[i] = lut[i];
  __syncthreads();

  int n = blockIdx.x * blockDim.x + t;
  if (n >= N_NODES) return;

  float d = fmaxf(deg[n], 1.0f);
  float dinv = 1.0f / d;

  float x[BATCH];
  const float4* av = (const float4*)(agg + (size_t)n * BATCH);
#pragma unroll
  for (int q = 0; q < 4; ++q) {
    float4 v = av[q];
    x[4 * q + 0] = v.x * dinv;
    x[4 * q + 1] = v.y * dinv;
    x[4 * q + 2] = v.z * dinv;
    x[4 * q + 3] = v.w * dinv;
  }

#pragma unroll
  for (int b = 0; b < BATCH; ++b) {
    float u = (x[b] - LUT_LO) * LUT_SCALE;
    u = fminf(fmaxf(u, 0.0f), (float)LUT_SIZE - 0.001f);
    int i = (int)u;
    float frac = u - (float)i;
    float lo = slut[i];
    float hi = slut[i + 1];
    out[(size_t)b * N_NODES + n] = fmaf(hi - lo, frac, lo);
  }
}

extern "C" void kernel_launch(void* const* d_in, const int* in_sizes, int n_in,
                              void* d_out, int out_size, void* d_ws, size_t ws_size,
                              hipStream_t stream) {
  const float* mu = (const float*)d_in[0];
  const int*   ei = (const int*)d_in[1];
  const float* W1 = (const float*)d_in[2];
  const float* b1 = (const float*)d_in[3];
  const float* W2 = (const float*)d_in[4];
  const float* b2 = (const float*)d_in[5];
  float* out = (float*)d_out;

  float* mu_t = (float*)d_ws;                           // [N*B]  6.4 MB
  float* agg  = mu_t + (size_t)N_NODES * BATCH;         // [N*B]  6.4 MB
  float* deg  = agg + (size_t)N_NODES * BATCH;          // [N]    0.4 MB
  float* lut  = deg + N_NODES;                          // [LUT_SIZE+1]

  // zero agg + deg only (mu_t / lut are fully overwritten each call)
  size_t zero_bytes = ((size_t)N_NODES * BATCH + N_NODES) * sizeof(float);
  hipMemsetAsync(agg, 0, zero_bytes, stream);

  transpose_kernel<<<(N_NODES + 255) / 256, 256, 0, stream>>>(mu, mu_t);
  build_lut_kernel<<<(LUT_SIZE + 1 + 255) / 256, 256, 0, stream>>>(W1, b1, W2, b2, lut);

  long long total = (long long)N_EDGES * BATCH;
  scatter_kernel<<<(int)((total + 255) / 256), 256, 0, stream>>>(ei, mu_t, agg, deg);
  apply_kernel<<<(N_NODES + 255) / 256, 256, 0, stream>>>(agg, deg, lut, out);
}